// Round 5
// baseline (4178.800 us; speedup 1.0000x reference)
//
#include <hip/hip_runtime.h>
#include <stdint.h>

#define M_DIM 8192
#define N_DIM 11008
#define K_DIM 4096

#define BM 256
#define BN 256
#define BK 64                    // 64 i8 elems = 64 B per row per tile
#define NT (K_DIM / BK)          // 64 K-tiles
#define GRID_M (M_DIM / BM)      // 32
#define GRID_N (N_DIM / BN)      // 43
#define NWG (GRID_M * GRID_N)    // 1376 (divisible by 8)

#define BUFB (BM * BK)           // 16384 bytes per tile-buffer per matrix

typedef int i32x4 __attribute__((ext_vector_type(4)));

__device__ __forceinline__ void gload16(const int8_t* src, int8_t* dst) {
    __builtin_amdgcn_global_load_lds(
        (const __attribute__((address_space(1))) uint32_t*)src,
        (__attribute__((address_space(3))) uint32_t*)dst, 16, 0, 0);
}

// ---------- pre-pass 1: per-row (token) absmax quant of x -> i8 + inv scale ----------
// one wave per row; 2048 blocks x 256 thr = 8192 waves = 8192 rows exactly.

__global__ __launch_bounds__(256) void quant_x_kernel(
    const float* __restrict__ x, int8_t* __restrict__ xq, float* __restrict__ sinv)
{
    const int wave = blockIdx.x * 4 + (threadIdx.x >> 6);
    const int lane = threadIdx.x & 63;
    const float* row = x + (size_t)wave * K_DIM;

    float4 v[16];
    float mx = 0.0f;
    #pragma unroll
    for (int j = 0; j < 16; ++j) {
        v[j] = *(const float4*)(row + (j * 64 + lane) * 4);
        mx = fmaxf(mx, fmaxf(fmaxf(fabsf(v[j].x), fabsf(v[j].y)),
                             fmaxf(fabsf(v[j].z), fabsf(v[j].w))));
    }
    #pragma unroll
    for (int off = 32; off > 0; off >>= 1)
        mx = fmaxf(mx, __shfl_xor(mx, off));
    if (mx < 1e-30f) mx = 1e-30f;
    const float s = 127.0f / mx;

    int8_t* orow = xq + (size_t)wave * K_DIM;
    #pragma unroll
    for (int j = 0; j < 16; ++j) {
        int a = (int)__builtin_rintf(v[j].x * s);
        int b = (int)__builtin_rintf(v[j].y * s);
        int c = (int)__builtin_rintf(v[j].z * s);
        int d = (int)__builtin_rintf(v[j].w * s);
        uint32_t p = (uint32_t)(a & 0xFF) | ((uint32_t)(b & 0xFF) << 8) |
                     ((uint32_t)(c & 0xFF) << 16) | ((uint32_t)(d & 0xFF) << 24);
        *(uint32_t*)(orow + (j * 64 + lane) * 4) = p;
    }
    if (lane == 0) sinv[wave] = mx / 127.0f;
}

// ---------- pre-pass 2: f32 w -> sign(w) in i8 (exact {-1,0,+1}) ----------

__global__ __launch_bounds__(256) void sign_w_kernel(
    const float* __restrict__ w, int8_t* __restrict__ wq, long long n16)
{
    long long i = (long long)blockIdx.x * blockDim.x + threadIdx.x;
    const long long stride = (long long)gridDim.x * blockDim.x;
    for (; i < n16; i += stride) {
        const float* src = w + i * 16;
        uint32_t pk[4];
        #pragma unroll
        for (int q = 0; q < 4; ++q) {
            float4 f = *(const float4*)(src + q * 4);
            int a = (f.x > 0.f) ? 1 : ((f.x < 0.f) ? -1 : 0);
            int b = (f.y > 0.f) ? 1 : ((f.y < 0.f) ? -1 : 0);
            int c = (f.z > 0.f) ? 1 : ((f.z < 0.f) ? -1 : 0);
            int d = (f.w > 0.f) ? 1 : ((f.w < 0.f) ? -1 : 0);
            pk[q] = (uint32_t)(a & 0xFF) | ((uint32_t)(b & 0xFF) << 8) |
                    ((uint32_t)(c & 0xFF) << 16) | ((uint32_t)(d & 0xFF) << 24);
        }
        *(i32x4*)(wq + i * 16) = (i32x4){(int)pk[0], (int)pk[1], (int)pk[2], (int)pk[3]};
    }
}

// ---------- main GEMM (i8): 256x256 tile, BK=64, 8 waves, 64 KiB LDS ->
// 2 blocks/CU (4 waves/SIMD). One phase per K-tile, ring-2 LDS dbuf. ----------
//
// mfma_i32_16x16x64_i8: A/B = 16 i8 per lane (4 VGPR), row = lane&15,
// k = (lane>>4)*16 + [0..16) contiguous (pattern of verified bf16 16x16x32).
// C/D layout dtype-independent (m121-128): col=lane&15, row=(lane>>4)*4+reg.
//
// Phase(t):  12 ds_read_b128 frags(t) from buf[t&1]
//            lgkmcnt(0); s_barrier            // all waves' reads of buf[t&1] done
//            stage(t+2) -> buf[t&1]           // WAR-safe; 4 gload_lds
//            MFMA x32 (frags already drained)
//            vmcnt(4) if t<=NT-3 else vmcnt(0) // drains stage(t+1) for next phase
//            s_barrier
// RAW: at phase(t) trailing wait, outstanding = stage(t+1)+stage(t+2) = 8;
// vmcnt(4) drains the older 4 = stage(t+1) -> tile t+1 complete in LDS before
// any wave reads it. In-flight window for stage(t+2) ≈ 1.5 phases.
//
// LDS bank swizzle: row stride 64 B -> naive 8-way conflict on ds_read_b128.
// slot' = slot ^ ((row>>1)&3): 16 lanes/quarter spread over 8 distinct 4-bank
// windows = 2 lanes/bank (free, m136). Inverse applied on global src (rule #21).

__global__ __launch_bounds__(512, 4) void ternary_gemm_i8(
    const int8_t* __restrict__ A, const int8_t* __restrict__ B,
    const float* __restrict__ bias, const float* __restrict__ sinv,
    float* __restrict__ out)
{
    extern __shared__ int8_t lds[];
    int8_t* As = lds;                 // [2][BUFB]
    int8_t* Bs = lds + 2 * BUFB;      // [2][BUFB]

    const int tid  = threadIdx.x;
    const int lane = tid & 63;
    const int wid  = tid >> 6;        // 0..7
    const int wm   = wid >> 2;        // 0..1
    const int wn   = wid & 3;         // 0..3
    const int l15  = lane & 15;
    const int l4   = lane >> 4;       // 0..3

    // T1: bijective XCD swizzle (NWG % 8 == 0), bn-minor for A-panel L2 reuse
    const int bid = blockIdx.x;
    const int swz = (bid & 7) * (NWG / 8) + (bid >> 3);
    const int bm  = swz / GRID_N;
    const int bn  = swz % GRID_N;
    const long brow = (long)bm * BM;
    const long bcol = (long)bn * BN;

    // ---- staging addressing ----
    // inst r covers tile-row r*128 + (tid>>2), 16B-slot tid&3; LDS dest linear
    // (dest_byte = r*8192 + tid*16). Global src slot = (tid&3) ^ ((tid>>3)&3).
    const int rowt = tid >> 2;                        // 0..127
    const int ssrc = (tid & 3) ^ ((tid >> 3) & 3);
    const int8_t* pA = A + (size_t)(brow + rowt) * K_DIM + ssrc * 16;
    const int8_t* pB = B + (size_t)(bcol + rowt) * K_DIM + ssrc * 16;

    auto stageA = [&](int t) {
        const int b = t & 1;
        #pragma unroll
        for (int r = 0; r < 2; ++r)
            gload16(pA + (size_t)r * 128 * K_DIM + (size_t)t * BK,
                    As + b * BUFB + r * 8192 + wid * 1024);
    };
    auto stageB = [&](int t) {
        const int b = t & 1;
        #pragma unroll
        for (int r = 0; r < 2; ++r)
            gload16(pB + (size_t)r * 128 * K_DIM + (size_t)t * BK,
                    Bs + b * BUFB + r * 8192 + wid * 1024);
    };

    // ---- fragment read addressing (swizzled slot, const per thread) ----
    const int slot = l4 ^ ((l15 >> 1) & 3);
    const int aOff = (wm * 16 + l15) * 64 + slot * 16;   // + m*32*64 = m*2048
    const int bOff = (wn * 16 + l15) * 64 + slot * 16;   // + n*64*64 = n*4096

    i32x4 acc[8][4];
    #pragma unroll
    for (int m = 0; m < 8; ++m)
        #pragma unroll
        for (int n = 0; n < 4; ++n) acc[m][n] = (i32x4){0, 0, 0, 0};

    // ---- prologue: stage tiles 0,1; wait tile 0 (vmcnt THEN barrier) ----
    stageA(0); stageB(0);
    stageA(1); stageB(1);
    asm volatile("s_waitcnt vmcnt(4)" ::: "memory");
    __builtin_amdgcn_s_barrier();
    __builtin_amdgcn_sched_barrier(0);

    for (int t = 0; t < NT; ++t) {
        const int b = t & 1;

        i32x4 ar[8], br[4];
        #pragma unroll
        for (int m = 0; m < 8; ++m)
            ar[m] = *(const i32x4*)(As + b * BUFB + m * 2048 + aOff);
        #pragma unroll
        for (int n = 0; n < 4; ++n)
            br[n] = *(const i32x4*)(Bs + b * BUFB + n * 4096 + bOff);
        __builtin_amdgcn_sched_barrier(0);
        asm volatile("s_waitcnt lgkmcnt(0)" ::: "memory");
        __builtin_amdgcn_s_barrier();            // all waves' reads of buf[b] done
        __builtin_amdgcn_sched_barrier(0);

        if (t + 2 < NT) { stageA(t + 2); stageB(t + 2); }   // -> buf[b], WAR-safe
        __builtin_amdgcn_sched_barrier(0);

        __builtin_amdgcn_s_setprio(1);
        #pragma unroll
        for (int m = 0; m < 8; ++m)
            #pragma unroll
            for (int n = 0; n < 4; ++n)
                acc[m][n] = __builtin_amdgcn_mfma_i32_16x16x64_i8(ar[m], br[n], acc[m][n], 0, 0, 0);
        __builtin_amdgcn_s_setprio(0);
        __builtin_amdgcn_sched_barrier(0);

        if (t <= NT - 3) { asm volatile("s_waitcnt vmcnt(4)" ::: "memory"); }
        else             { asm volatile("s_waitcnt vmcnt(0)" ::: "memory"); }
        __builtin_amdgcn_s_barrier();
        __builtin_amdgcn_sched_barrier(0);
    }

    // ---- epilogue: out = acc * sinv[row] + bias[col] ----
    int   cols[4];
    float bv[4];
    #pragma unroll
    for (int n = 0; n < 4; ++n) {
        cols[n] = (int)bcol + n * 64 + wn * 16 + l15;
        bv[n] = bias[cols[n]];
    }
    #pragma unroll
    for (int m = 0; m < 8; ++m) {
        const size_t row0 = (size_t)brow + m * 32 + wm * 16 + l4 * 4;
        float s0 = sinv[row0], s1 = sinv[row0 + 1], s2 = sinv[row0 + 2], s3 = sinv[row0 + 3];
        #pragma unroll
        for (int n = 0; n < 4; ++n) {
            out[(row0 + 0) * N_DIM + cols[n]] = (float)acc[m][n][0] * s0 + bv[n];
            out[(row0 + 1) * N_DIM + cols[n]] = (float)acc[m][n][1] * s1 + bv[n];
            out[(row0 + 2) * N_DIM + cols[n]] = (float)acc[m][n][2] * s2 + bv[n];
            out[(row0 + 3) * N_DIM + cols[n]] = (float)acc[m][n][3] * s3 + bv[n];
        }
    }
}

// ---------- fallback (only if workspace too small): correct but slow ----------

__global__ void naive_kernel(const float* __restrict__ x, const float* __restrict__ w,
                             const float* __restrict__ bias, float* __restrict__ out) {
    long long o = (long long)blockIdx.x * blockDim.x + threadIdx.x;
    if (o >= (long long)M_DIM * N_DIM) return;
    int row = (int)(o / N_DIM), col = (int)(o % N_DIM);
    float s = 0.0f;
    const float* xr = x + (size_t)row * K_DIM;
    const float* wr = w + (size_t)col * K_DIM;
    for (int k = 0; k < K_DIM; ++k) {
        float wv = wr[k];
        s += (wv > 0.0f) ? xr[k] : ((wv < 0.0f) ? -xr[k] : 0.0f);
    }
    out[o] = s + bias[col];
}

// ---------- launch ----------

extern "C" void kernel_launch(void* const* d_in, const int* in_sizes, int n_in,
                              void* d_out, int out_size, void* d_ws, size_t ws_size,
                              hipStream_t stream) {
    const float* x    = (const float*)d_in[0];
    const float* w    = (const float*)d_in[1];
    const float* bias = (const float*)d_in[2];
    float* out        = (float*)d_out;

    const size_t xq_bytes = (size_t)M_DIM * K_DIM;        // 33.6 MB
    const size_t wq_bytes = (size_t)N_DIM * K_DIM;        // 45.1 MB
    const size_t si_bytes = (size_t)M_DIM * sizeof(float);

    if (ws_size >= xq_bytes + wq_bytes + si_bytes) {
        int8_t* xq   = (int8_t*)d_ws;
        int8_t* wq   = (int8_t*)((char*)d_ws + xq_bytes);
        float*  sinv = (float*)((char*)d_ws + xq_bytes + wq_bytes);

        quant_x_kernel<<<M_DIM / 4, 256, 0, stream>>>(x, xq, sinv);
        const long long n16 = ((long long)N_DIM * K_DIM) / 16;
        sign_w_kernel<<<2048, 256, 0, stream>>>(w, wq, n16);

        hipFuncSetAttribute(reinterpret_cast<const void*>(ternary_gemm_i8),
                            hipFuncAttributeMaxDynamicSharedMemorySize, 4 * BUFB);
        ternary_gemm_i8<<<NWG, 512, 4 * BUFB, stream>>>(xq, wq, bias, sinv, out);
    } else {
        const long long total = (long long)M_DIM * N_DIM;
        naive_kernel<<<(int)((total + 255) / 256), 256, 0, stream>>>(x, w, bias, out);
    }
}

// Round 6
// 497.346 us; speedup vs baseline: 8.4022x; 8.4022x over previous
//
#include <hip/hip_runtime.h>
#include <stdint.h>

#define M_DIM 8192
#define N_DIM 11008
#define K_DIM 4096

#define BM 256
#define BN 256
#define BK 64                    // 64 i8 elems = 64 B per row per tile
#define NT (K_DIM / BK)          // 64 K-tiles
#define GRID_M (M_DIM / BM)      // 32
#define GRID_N (N_DIM / BN)      // 43
#define NWG (GRID_M * GRID_N)    // 1376 (divisible by 8)

#define BUFB (BM * BK)           // 16384 bytes per tile-buffer per matrix

typedef int i32x4 __attribute__((ext_vector_type(4)));

__device__ __forceinline__ void gload16(const int8_t* src, int8_t* dst) {
    __builtin_amdgcn_global_load_lds(
        (const __attribute__((address_space(1))) uint32_t*)src,
        (__attribute__((address_space(3))) uint32_t*)dst, 16, 0, 0);
}

// ---------- pre-pass 1: per-row (token) absmax quant of x -> i8 + inv scale ----------

__global__ __launch_bounds__(256) void quant_x_kernel(
    const float* __restrict__ x, int8_t* __restrict__ xq, float* __restrict__ sinv)
{
    const int wave = blockIdx.x * 4 + (threadIdx.x >> 6);
    const int lane = threadIdx.x & 63;
    const float* row = x + (size_t)wave * K_DIM;

    float4 v[16];
    float mx = 0.0f;
    #pragma unroll
    for (int j = 0; j < 16; ++j) {
        v[j] = *(const float4*)(row + (j * 64 + lane) * 4);
        mx = fmaxf(mx, fmaxf(fmaxf(fabsf(v[j].x), fabsf(v[j].y)),
                             fmaxf(fabsf(v[j].z), fabsf(v[j].w))));
    }
    #pragma unroll
    for (int off = 32; off > 0; off >>= 1)
        mx = fmaxf(mx, __shfl_xor(mx, off));
    if (mx < 1e-30f) mx = 1e-30f;
    const float s = 127.0f / mx;

    int8_t* orow = xq + (size_t)wave * K_DIM;
    #pragma unroll
    for (int j = 0; j < 16; ++j) {
        int a = (int)__builtin_rintf(v[j].x * s);
        int b = (int)__builtin_rintf(v[j].y * s);
        int c = (int)__builtin_rintf(v[j].z * s);
        int d = (int)__builtin_rintf(v[j].w * s);
        uint32_t p = (uint32_t)(a & 0xFF) | ((uint32_t)(b & 0xFF) << 8) |
                     ((uint32_t)(c & 0xFF) << 16) | ((uint32_t)(d & 0xFF) << 24);
        *(uint32_t*)(orow + (j * 64 + lane) * 4) = p;
    }
    if (lane == 0) sinv[wave] = mx / 127.0f;
}

// ---------- pre-pass 2: f32 w -> sign(w) in i8 (exact {-1,0,+1}) ----------

__global__ __launch_bounds__(256) void sign_w_kernel(
    const float* __restrict__ w, int8_t* __restrict__ wq, long long n16)
{
    long long i = (long long)blockIdx.x * blockDim.x + threadIdx.x;
    const long long stride = (long long)gridDim.x * blockDim.x;
    for (; i < n16; i += stride) {
        const float* src = w + i * 16;
        uint32_t pk[4];
        #pragma unroll
        for (int q = 0; q < 4; ++q) {
            float4 f = *(const float4*)(src + q * 4);
            int a = (f.x > 0.f) ? 1 : ((f.x < 0.f) ? -1 : 0);
            int b = (f.y > 0.f) ? 1 : ((f.y < 0.f) ? -1 : 0);
            int c = (f.z > 0.f) ? 1 : ((f.z < 0.f) ? -1 : 0);
            int d = (f.w > 0.f) ? 1 : ((f.w < 0.f) ? -1 : 0);
            pk[q] = (uint32_t)(a & 0xFF) | ((uint32_t)(b & 0xFF) << 8) |
                    ((uint32_t)(c & 0xFF) << 16) | ((uint32_t)(d & 0xFF) << 24);
        }
        *(i32x4*)(wq + i * 16) = (i32x4){(int)pk[0], (int)pk[1], (int)pk[2], (int)pk[3]};
    }
}

// ---------- main GEMM (i8): 256x256 tile, BK=64, 8 waves, RING-3 LDS (96 KiB).
// launch_bounds(512,2): 256-unified-reg cap -> NO SPILL (r5 lesson: (512,4)'s
// 128-reg cap spilled acc -> 19 GB scratch traffic).
//
// mfma_i32_16x16x64_i8: A/B = 16 i8/lane (4 VGPR), row=lane&15,
// k=(lane>>4)*16+[0..16). C/D dtype-independent: col=lane&15, row=(lane>>4)*4+reg.
//
// Ring-3 schedule, phase(t) [buf slot b = t % 3]:
//   12 ds_read_b128 frags(t) from buf[b]      (tile t landed: see RAW below)
//   lgkmcnt(0); s_barrier                      // all waves' reads of buf[b] done
//   stage(t+3) -> buf[(t+3)%3] == buf[b]       // WAR-safe (post-barrier)
//   MFMA x32
//   trailing wait + s_barrier:
//     t <= NT-4: vmcnt(8)   in-flight {t+1,t+2,t+3}x4 -> drains stage(t+1)
//     t == NT-3: vmcnt(4)   in-flight {t+2,t+3<NT? no}= {62,63}x4 -> drains 62
//     else:      vmcnt(0)
// RAW: stage(t) drained by phase(t-1)'s trailing wait (+barrier -> all waves).
// Slack for stage(t+1): issued at phase(t-2) mid, waited end phase(t) ~ 2.5
// phases (~8000 cy) >> loaded HBM latency -> trailing wait ~free.

__global__ __launch_bounds__(512, 2) void ternary_gemm_i8(
    const int8_t* __restrict__ A, const int8_t* __restrict__ B,
    const float* __restrict__ bias, const float* __restrict__ sinv,
    float* __restrict__ out)
{
    extern __shared__ int8_t lds[];
    int8_t* As = lds;                 // [3][BUFB]
    int8_t* Bs = lds + 3 * BUFB;      // [3][BUFB]

    const int tid  = threadIdx.x;
    const int lane = tid & 63;
    const int wid  = tid >> 6;        // 0..7
    const int wm   = wid >> 2;        // 0..1
    const int wn   = wid & 3;         // 0..3
    const int l15  = lane & 15;
    const int l4   = lane >> 4;       // 0..3

    // T1: bijective XCD swizzle (NWG % 8 == 0), bn-minor for A-panel L2 reuse
    const int bid = blockIdx.x;
    const int swz = (bid & 7) * (NWG / 8) + (bid >> 3);
    const int bm  = swz / GRID_N;
    const int bn  = swz % GRID_N;
    const long brow = (long)bm * BM;
    const long bcol = (long)bn * BN;

    // ---- staging addressing ----
    // inst r covers tile-row r*128 + (tid>>2), 16B-slot tid&3; LDS dest linear
    // (dest_byte = r*8192 + tid*16). Global src slot = (tid&3) ^ ((tid>>3)&3)
    // (inverse of read-side swizzle slot^((row>>1)&3), row = tid>>2).
    const int rowt = tid >> 2;                        // 0..127
    const int ssrc = (tid & 3) ^ ((tid >> 3) & 3);
    const int8_t* pA = A + (size_t)(brow + rowt) * K_DIM + ssrc * 16;
    const int8_t* pB = B + (size_t)(bcol + rowt) * K_DIM + ssrc * 16;

    auto stageAB = [&](int t, int bslot) {
        #pragma unroll
        for (int r = 0; r < 2; ++r)
            gload16(pA + (size_t)r * 128 * K_DIM + (size_t)t * BK,
                    As + bslot * BUFB + r * 8192 + wid * 1024);
        #pragma unroll
        for (int r = 0; r < 2; ++r)
            gload16(pB + (size_t)r * 128 * K_DIM + (size_t)t * BK,
                    Bs + bslot * BUFB + r * 8192 + wid * 1024);
    };

    // ---- fragment read addressing (swizzled slot, const per thread) ----
    const int slot = l4 ^ ((l15 >> 1) & 3);
    const int aOff = (wm * 16 + l15) * 64 + slot * 16;   // + m*2048
    const int bOff = (wn * 16 + l15) * 64 + slot * 16;   // + n*4096

    i32x4 acc[8][4];
    #pragma unroll
    for (int m = 0; m < 8; ++m)
        #pragma unroll
        for (int n = 0; n < 4; ++n) acc[m][n] = (i32x4){0, 0, 0, 0};

    // ---- prologue: stage tiles 0,1,2; drain tile 0 (vmcnt THEN barrier) ----
    stageAB(0, 0);
    stageAB(1, 1);
    stageAB(2, 2);
    asm volatile("s_waitcnt vmcnt(8)" ::: "memory");
    __builtin_amdgcn_s_barrier();
    __builtin_amdgcn_sched_barrier(0);

    int bcur = 0;
    for (int t = 0; t < NT; ++t) {
        const int b = bcur;

        i32x4 ar[8], br[4];
        #pragma unroll
        for (int m = 0; m < 8; ++m)
            ar[m] = *(const i32x4*)(As + b * BUFB + m * 2048 + aOff);
        #pragma unroll
        for (int n = 0; n < 4; ++n)
            br[n] = *(const i32x4*)(Bs + b * BUFB + n * 4096 + bOff);
        __builtin_amdgcn_sched_barrier(0);
        asm volatile("s_waitcnt lgkmcnt(0)" ::: "memory");
        __builtin_amdgcn_s_barrier();            // all waves' reads of buf[b] done
        __builtin_amdgcn_sched_barrier(0);

        if (t + 3 < NT) stageAB(t + 3, b);       // -> same slot, WAR-safe
        __builtin_amdgcn_sched_barrier(0);

        __builtin_amdgcn_s_setprio(1);
        #pragma unroll
        for (int m = 0; m < 8; ++m)
            #pragma unroll
            for (int n = 0; n < 4; ++n)
                acc[m][n] = __builtin_amdgcn_mfma_i32_16x16x64_i8(ar[m], br[n], acc[m][n], 0, 0, 0);
        __builtin_amdgcn_s_setprio(0);
        __builtin_amdgcn_sched_barrier(0);

        if (t <= NT - 4)      { asm volatile("s_waitcnt vmcnt(8)" ::: "memory"); }
        else if (t == NT - 3) { asm volatile("s_waitcnt vmcnt(4)" ::: "memory"); }
        else                  { asm volatile("s_waitcnt vmcnt(0)" ::: "memory"); }
        __builtin_amdgcn_s_barrier();
        __builtin_amdgcn_sched_barrier(0);

        bcur = (bcur == 2) ? 0 : bcur + 1;
    }

    // ---- epilogue: out = acc * sinv[row] + bias[col] ----
    int   cols[4];
    float bv[4];
    #pragma unroll
    for (int n = 0; n < 4; ++n) {
        cols[n] = (int)bcol + n * 64 + wn * 16 + l15;
        bv[n] = bias[cols[n]];
    }
    #pragma unroll
    for (int m = 0; m < 8; ++m) {
        const size_t row0 = (size_t)brow + m * 32 + wm * 16 + l4 * 4;
        float s0 = sinv[row0], s1 = sinv[row0 + 1], s2 = sinv[row0 + 2], s3 = sinv[row0 + 3];
        #pragma unroll
        for (int n = 0; n < 4; ++n) {
            out[(row0 + 0) * N_DIM + cols[n]] = (float)acc[m][n][0] * s0 + bv[n];
            out[(row0 + 1) * N_DIM + cols[n]] = (float)acc[m][n][1] * s1 + bv[n];
            out[(row0 + 2) * N_DIM + cols[n]] = (float)acc[m][n][2] * s2 + bv[n];
            out[(row0 + 3) * N_DIM + cols[n]] = (float)acc[m][n][3] * s3 + bv[n];
        }
    }
}

// ---------- fallback (only if workspace too small): correct but slow ----------

__global__ void naive_kernel(const float* __restrict__ x, const float* __restrict__ w,
                             const float* __restrict__ bias, float* __restrict__ out) {
    long long o = (long long)blockIdx.x * blockDim.x + threadIdx.x;
    if (o >= (long long)M_DIM * N_DIM) return;
    int row = (int)(o / N_DIM), col = (int)(o % N_DIM);
    float s = 0.0f;
    const float* xr = x + (size_t)row * K_DIM;
    const float* wr = w + (size_t)col * K_DIM;
    for (int k = 0; k < K_DIM; ++k) {
        float wv = wr[k];
        s += (wv > 0.0f) ? xr[k] : ((wv < 0.0f) ? -xr[k] : 0.0f);
    }
    out[o] = s + bias[col];
}

// ---------- launch ----------

extern "C" void kernel_launch(void* const* d_in, const int* in_sizes, int n_in,
                              void* d_out, int out_size, void* d_ws, size_t ws_size,
                              hipStream_t stream) {
    const float* x    = (const float*)d_in[0];
    const float* w    = (const float*)d_in[1];
    const float* bias = (const float*)d_in[2];
    float* out        = (float*)d_out;

    const size_t xq_bytes = (size_t)M_DIM * K_DIM;        // 33.6 MB
    const size_t wq_bytes = (size_t)N_DIM * K_DIM;        // 45.1 MB
    const size_t si_bytes = (size_t)M_DIM * sizeof(float);

    if (ws_size >= xq_bytes + wq_bytes + si_bytes) {
        int8_t* xq   = (int8_t*)d_ws;
        int8_t* wq   = (int8_t*)((char*)d_ws + xq_bytes);
        float*  sinv = (float*)((char*)d_ws + xq_bytes + wq_bytes);

        quant_x_kernel<<<M_DIM / 4, 256, 0, stream>>>(x, xq, sinv);
        const long long n16 = ((long long)N_DIM * K_DIM) / 16;
        sign_w_kernel<<<2048, 256, 0, stream>>>(w, wq, n16);

        hipFuncSetAttribute(reinterpret_cast<const void*>(ternary_gemm_i8),
                            hipFuncAttributeMaxDynamicSharedMemorySize, 6 * BUFB);
        ternary_gemm_i8<<<NWG, 512, 6 * BUFB, stream>>>(xq, wq, bias, sinv, out);
    } else {
        const long long total = (long long)M_DIM * N_DIM;
        naive_kernel<<<(int)((total + 255) / 256), 256, 0, stream>>>(x, w, bias, out);
    }
}